// Round 5
// baseline (705.365 us; speedup 1.0000x reference)
//
#include <hip/hip_runtime.h>

#define NROWS 131072
#define KDIM 512
#define NDIM 512

using short8  = __attribute__((ext_vector_type(8))) short;
using float4v = __attribute__((ext_vector_type(4))) float;
using uint4v  = __attribute__((ext_vector_type(4))) unsigned int;

// pack two fp32 -> bf16x2 (truncation; 1 v_perm per pair)
__device__ __forceinline__ unsigned pack_trunc(float a, float b) {
    unsigned ua = __builtin_bit_cast(unsigned, a);
    unsigned ub = __builtin_bit_cast(unsigned, b);
    return __builtin_amdgcn_perm(ub, ua, 0x07060302u);
}
// pack two fp32 -> bf16x2 (round-half-up on magnitude; off hot path)
__device__ __forceinline__ unsigned pack_round(float a, float b) {
    unsigned ua = __builtin_bit_cast(unsigned, a) + 0x8000u;
    unsigned ub = __builtin_bit_cast(unsigned, b) + 0x8000u;
    return __builtin_amdgcn_perm(ub, ua, 0x07060302u);
}

// async global->LDS, 16B per lane. LDS dest must be wave-uniform base + lane*16.
__device__ __forceinline__ void glds16(const void* g, void* l) {
    __builtin_amdgcn_global_load_lds(
        (__attribute__((address_space(1))) void*)g,
        (__attribute__((address_space(3))) void*)l, 16, 0, 0);
}

// Pass 1 (merged): blocks [0,512): W fp32 -> Wt bf16 transposed
//                  blocks [512,2560): x fp32 -> xb bf16 streaming
__global__ __launch_bounds__(256) void prep_kernel(const float* __restrict__ w,
                                                   unsigned short* __restrict__ wt,
                                                   const float* __restrict__ x,
                                                   unsigned short* __restrict__ xb) {
    __shared__ float tile[64][65];
    if (blockIdx.x < 512) {
        int b  = blockIdx.x;
        int ty = b >> 6;              // type 0..7
        int ot = (b >> 3) & 7;        // out-tile of 64
        int it = b & 7;               // in-tile of 64
        const float* wp = w + ((size_t)ty << 18);
        int tid = threadIdx.x;
        int cf = tid & 15, ir0 = tid >> 4;
        #pragma unroll
        for (int j = 0; j < 4; ++j) {
            int ir = ir0 + 16 * j;
            float4v v = *(const float4v*)(wp + (size_t)(it * 64 + ir) * NDIM + ot * 64 + cf * 4);
            tile[ir][cf * 4 + 0] = v.x;
            tile[ir][cf * 4 + 1] = v.y;
            tile[ir][cf * 4 + 2] = v.z;
            tile[ir][cf * 4 + 3] = v.w;
        }
        __syncthreads();
        int oc = tid >> 2, iq = tid & 3;
        unsigned* op = (unsigned*)(wt + ((size_t)ty << 18) + (size_t)(ot * 64 + oc) * KDIM + it * 64 + iq * 16);
        #pragma unroll
        for (int j = 0; j < 8; ++j)
            op[j] = pack_round(tile[iq * 16 + 2 * j][oc], tile[iq * 16 + 2 * j + 1][oc]);
    } else {
        const size_t total = (size_t)NROWS * KDIM / 8;   // 8 floats per thread-iter
        size_t i = (size_t)(blockIdx.x - 512) * 256 + threadIdx.x;
        const size_t stride = (size_t)2048 * 256;
        const float4v* xv = (const float4v*)x;
        uint4v* ov = (uint4v*)xb;
        for (; i < total; i += stride) {
            float4v a = __builtin_nontemporal_load(&xv[2 * i]);
            float4v c = __builtin_nontemporal_load(&xv[2 * i + 1]);
            uint4v o;
            o.x = pack_round(a.x, a.y);
            o.y = pack_round(a.z, a.w);
            o.z = pack_round(c.x, c.y);
            o.w = pack_round(c.z, c.w);
            ov[i] = o;   // plain store: keep xb L3-resident for the GEMM
        }
    }
}

// ---------------------------------------------------------------------------
// Pass 2: m201-style 8-phase 256x256 GEMM. 512 threads = 8 waves (2 M x 4 N),
// BK=64, LDS 128 KiB: lds[slot 2][seg: A0,A1,B0,B1][1024 units of 16B].
// K-outer unit layout (kgrp*128 + idx): glds-linear AND conflict-free ds_read
// (0 bank conflicts measured r3/r4) -> no XOR swizzle needed.
// Staging schedule (iter consumes kt@p0-3 [slot0], kt+1@p4-7 [slot1]):
//   p0,p1: A(kt+1)->slot1   (A(kt-1) last read prev iter p6)
//   p2,p3: B(kt+2)->slot0   (B(kt)   last read p1)
//   p4,p5: A(kt+2)->slot0   (A(kt)   last read p2)
//   p6,p7: B(kt+3)->slot1   (B(kt+1) last read p5)
// vmcnt(4) before the closing barrier of p3 and p7: guarantees the 4 oldest
// in-flight glds-pairs (= next-needed A+B tile, staged >=4 phases earlier)
// have landed; 2 half-tiles stay in flight across the barrier. Tail iter
// drains 4->0. Rule #18: lgkmcnt(0) asm is followed by sched_barrier(0).
// ---------------------------------------------------------------------------
__global__ __launch_bounds__(512, 1)
void hetero_gemm_256(const unsigned short* __restrict__ xb,
                     const int* __restrict__ tv,
                     const unsigned short* __restrict__ wt,
                     const float* __restrict__ bias,
                     float* __restrict__ out) {
    __shared__ uint4v lds[2][4][1024];   // 128 KiB

    // XCD swizzle (1024 % 8 == 0 -> simple bijective form): each XCD gets a
    // contiguous run of logical blocks; col-tile pairs of a row-tile co-locate.
    const int bhw = blockIdx.x;
    const int b = (bhw & 7) * 128 + (bhw >> 3);
    const int rowTile = b >> 1;           // 0..511
    const int colTile = b & 1;            // 0..1
    const int row0 = rowTile << 8;
    const int col0 = colTile << 8;

    const int tid  = threadIdx.x;
    const int lane = tid & 63;
    const int wid  = tid >> 6;            // 0..7
    const int wr   = wid >> 2;            // 0..1  (M half)
    const int wc   = wid & 3;             // 0..3  (N quarter)
    const int l15  = lane & 15;
    const int quad = lane >> 4;
    const int segB  = 2 + (wc >> 1);      // B seg this wave reads
    const int cbase = (wc & 1) * 64;      // col base within seg

    const int t0 = tv[row0];
    const int t1 = tv[row0 + 255];

    const unsigned short* aPanel = xb + (size_t)row0 * KDIM;

#define RD_A(SL, H)                                                           \
    do {                                                                      \
        _Pragma("unroll")                                                     \
        for (int kk = 0; kk < 2; ++kk)                                        \
            _Pragma("unroll")                                                 \
            for (int j = 0; j < 4; ++j)                                       \
                afr[kk][j] = *(const short8*)&lds[SL][wr]                     \
                    [(kk * 4 + quad) * 128 + (H) * 64 + j * 16 + l15];        \
    } while (0)

#define RD_B(SL, V)                                                           \
    do {                                                                      \
        _Pragma("unroll")                                                     \
        for (int kk = 0; kk < 2; ++kk)                                        \
            _Pragma("unroll")                                                 \
            for (int i = 0; i < 2; ++i)                                       \
                bfr[kk][(V) * 2 + i] = *(const short8*)&lds[SL][segB]         \
                    [(kk * 4 + quad) * 128 + cbase + ((V) * 2 + i) * 16 + l15]; \
    } while (0)

#define MMA(H, V)                                                             \
    do {                                                                      \
        __builtin_amdgcn_s_setprio(1);                                        \
        _Pragma("unroll")                                                     \
        for (int j = 0; j < 4; ++j)                                           \
            _Pragma("unroll")                                                 \
            for (int i = 0; i < 2; ++i)                                       \
                _Pragma("unroll")                                             \
                for (int kk = 0; kk < 2; ++kk)                                \
                    acc[(H) * 4 + j][(V) * 2 + i] =                           \
                        __builtin_amdgcn_mfma_f32_16x16x32_bf16(              \
                            afr[kk][j], bfr[kk][(V) * 2 + i],                 \
                            acc[(H) * 4 + j][(V) * 2 + i], 0, 0, 0);          \
        __builtin_amdgcn_s_setprio(0);                                        \
    } while (0)

#define ST_A(SL, H, KT)                                                       \
    do {                                                                      \
        const unsigned short* g_ = aPanel +                                   \
            (size_t)((H) * 128 + (tid & 127)) * KDIM + (KT) * 64 + (tid >> 7) * 8; \
        glds16(g_,      &lds[SL][H][tid]);                                    \
        glds16(g_ + 32, &lds[SL][H][tid + 512]);                              \
    } while (0)

#define ST_B(SL, G, KT)                                                       \
    do {                                                                      \
        const unsigned short* g_ = wPanel +                                   \
            (size_t)((G) * 128 + (tid & 127)) * KDIM + (KT) * 64 + (tid >> 7) * 8; \
        glds16(g_,      &lds[SL][2 + (G)][tid]);                              \
        glds16(g_ + 32, &lds[SL][2 + (G)][tid + 512]);                        \
    } while (0)

#define BAR()  __builtin_amdgcn_s_barrier()
#define PH_SYNC()                                                             \
    do {                                                                      \
        __builtin_amdgcn_s_barrier();                                         \
        asm volatile("s_waitcnt lgkmcnt(0)" ::: "memory");                    \
        __builtin_amdgcn_sched_barrier(0);                                    \
    } while (0)
#define VMW4() asm volatile("s_waitcnt vmcnt(4)" ::: "memory")
#define VMW0() asm volatile("s_waitcnt vmcnt(0)" ::: "memory")

    for (int tt = t0; tt <= t1; ++tt) {
        const unsigned short* wPanel = wt + ((size_t)tt << 18) + (size_t)col0 * KDIM;

        float4v acc[8][4];
        float4v zero = {0.f, 0.f, 0.f, 0.f};
        #pragma unroll
        for (int mi = 0; mi < 8; ++mi)
            #pragma unroll
            for (int ni = 0; ni < 4; ++ni)
                acc[mi][ni] = zero;

        short8 afr[2][4];   // [kk][j]  current H-half A fragments
        short8 bfr[2][4];   // [kk][ni] B fragments, both V halves live

        // prologue: B(0), A(0), B(1) in flight; wait oldest 4 pairs (A0,B0)
        ST_B(0, 0, 0); ST_B(0, 1, 0);
        ST_A(0, 0, 0); ST_A(0, 1, 0);
        ST_B(1, 0, 1); ST_B(1, 1, 1);
        VMW4();
        BAR();

        #pragma unroll
        for (int it = 0; it < 4; ++it) {
            const int kt = it * 2;
            // ---- phase 0: read A[h0],B[v0] of kt; stage A0(kt+1)
            RD_A(0, 0); RD_B(0, 0);
            ST_A(1, 0, kt + 1);
            PH_SYNC();
            MMA(0, 0);
            BAR();
            // ---- phase 1: read B[v1]; stage A1(kt+1)
            RD_B(0, 1);
            ST_A(1, 1, kt + 1);
            PH_SYNC();
            MMA(0, 1);
            BAR();
            // ---- phase 2: read A[h1]; stage B0(kt+2)
            RD_A(0, 1);
            if (it < 3) ST_B(0, 0, kt + 2);
            PH_SYNC();
            MMA(1, 1);
            BAR();
            // ---- phase 3: no reads; stage B1(kt+2); vmcnt before barrier
            if (it < 3) ST_B(0, 1, kt + 2);
            BAR();
            MMA(1, 0);
            if (it < 3) { VMW4(); } else { VMW0(); }
            BAR();
            // ---- phase 4: read A[h0],B[v0] of kt+1; stage A0(kt+2)
            RD_A(1, 0); RD_B(1, 0);
            if (it < 3) ST_A(0, 0, kt + 2);
            PH_SYNC();
            MMA(0, 0);
            BAR();
            // ---- phase 5: read B[v1]; stage A1(kt+2)
            RD_B(1, 1);
            if (it < 3) ST_A(0, 1, kt + 2);
            PH_SYNC();
            MMA(0, 1);
            BAR();
            // ---- phase 6: read A[h1]; stage B0(kt+3)
            RD_A(1, 1);
            if (it < 3) ST_B(1, 0, kt + 3);
            PH_SYNC();
            MMA(1, 1);
            BAR();
            // ---- phase 7: no reads; stage B1(kt+3); vmcnt before barrier
            if (it < 3) ST_B(1, 1, kt + 3);
            BAR();
            MMA(1, 0);
            if (it < 3) { VMW4(); } else { VMW0(); }
            BAR();
        }

        // epilogue: D row = quad*4+reg, col = lane&15 (m89-verified layout)
        float bcol[4];
        #pragma unroll
        for (int ni = 0; ni < 4; ++ni)
            bcol[ni] = bias[(size_t)tt * NDIM + col0 + wc * 64 + ni * 16 + l15];

        #pragma unroll
        for (int mi = 0; mi < 8; ++mi) {
            #pragma unroll
            for (int r = 0; r < 4; ++r) {
                const int grow = row0 + wr * 128 + mi * 16 + quad * 4 + r;
                if (tv[grow] == tt) {
                    float* orow = out + (size_t)grow * NDIM;
                    #pragma unroll
                    for (int ni = 0; ni < 4; ++ni) {
                        const int gcol = col0 + wc * 64 + ni * 16 + l15;
                        orow[gcol] = acc[mi][ni][r] + bcol[ni];
                    }
                }
            }
        }
    }
#undef RD_A
#undef RD_B
#undef MMA
#undef ST_A
#undef ST_B
#undef BAR
#undef PH_SYNC
#undef VMW4
#undef VMW0
}

// Fallback (workspace too small for xb): round-0 proven kernel.
__global__ __launch_bounds__(256, 2)
void hetero_gemm_fallback(const float* __restrict__ x,
                          const int* __restrict__ tv,
                          const unsigned short* __restrict__ wt,
                          const float* __restrict__ bias,
                          float* __restrict__ out) {
    __shared__ uint4v ldsA[4 * 128];
    __shared__ uint4v ldsB[4 * 128];

    const int b = blockIdx.x;
    const int rowTile = ((b >> 5) << 3) | (b & 7);
    const int colTile = (b >> 3) & 3;
    const int row0 = rowTile << 7;
    const int col0 = colTile << 7;

    const int tid  = threadIdx.x;
    const int lane = tid & 63;
    const int wave = tid >> 6;
    const int wm   = (wave & 1) << 6;
    const int wn   = (wave >> 1) << 6;
    const int l15  = lane & 15;
    const int quad = lane >> 4;

    const int ra = tid >> 1;
    const int khalf = tid & 1;
    const int rtypeA = tv[row0 + ra];

    const int nb = tid & 127;
    const int g2 = tid >> 7;

    const int t0 = tv[row0];
    const int t1 = tv[row0 + 127];

    float4v acc[4][4];
    float4v zero = {0.f, 0.f, 0.f, 0.f};
    #pragma unroll
    for (int i = 0; i < 4; ++i)
        #pragma unroll
        for (int j = 0; j < 4; ++j)
            acc[i][j] = zero;

    for (int tt = t0; tt <= t1; ++tt) {
        const unsigned maskA = (rtypeA == tt) ? 0xFFFFFFFFu : 0u;
        const float* ap = x + (size_t)(row0 + ra) * KDIM + khalf * 16;
        const unsigned short* wb = wt + ((size_t)tt << 18) + (size_t)(col0 + nb) * KDIM;

        float4v av[4];
        uint4v  bv[2];
        #pragma unroll
        for (int i = 0; i < 4; ++i) av[i] = *(const float4v*)(ap + i * 4);
        bv[0] = *(const uint4v*)(wb + g2 * 8);
        bv[1] = *(const uint4v*)(wb + (g2 + 2) * 8);

        for (int kc = 0; kc < KDIM; kc += 32) {
            __syncthreads();
            uint4v pa0, pa1;
            pa0.x = pack_trunc(av[0].x, av[0].y) & maskA;
            pa0.y = pack_trunc(av[0].z, av[0].w) & maskA;
            pa0.z = pack_trunc(av[1].x, av[1].y) & maskA;
            pa0.w = pack_trunc(av[1].z, av[1].w) & maskA;
            pa1.x = pack_trunc(av[2].x, av[2].y) & maskA;
            pa1.y = pack_trunc(av[2].z, av[2].w) & maskA;
            pa1.z = pack_trunc(av[3].x, av[3].y) & maskA;
            pa1.w = pack_trunc(av[3].z, av[3].w) & maskA;
            ldsA[(khalf * 2 + 0) * 128 + ra] = pa0;
            ldsA[(khalf * 2 + 1) * 128 + ra] = pa1;
            ldsB[(g2    ) * 128 + nb] = bv[0];
            ldsB[(g2 + 2) * 128 + nb] = bv[1];
            __syncthreads();

            if (kc + 32 < KDIM) {
                const float* ap2 = ap + kc + 32;
                #pragma unroll
                for (int i = 0; i < 4; ++i) av[i] = *(const float4v*)(ap2 + i * 4);
                const unsigned short* wb2 = wb + kc + 32;
                bv[0] = *(const uint4v*)(wb2 + g2 * 8);
                bv[1] = *(const uint4v*)(wb2 + (g2 + 2) * 8);
            }

            short8 af[4], bf[4];
            #pragma unroll
            for (int mi = 0; mi < 4; ++mi)
                af[mi] = *(const short8*)&ldsA[quad * 128 + wm + mi * 16 + l15];
            #pragma unroll
            for (int ni = 0; ni < 4; ++ni)
                bf[ni] = *(const short8*)&ldsB[quad * 128 + wn + ni * 16 + l15];
            #pragma unroll
            for (int mi = 0; mi < 4; ++mi)
                #pragma unroll
                for (int ni = 0; ni < 4; ++ni)
                    acc[mi][ni] = __builtin_amdgcn_mfma_f32_16x16x32_bf16(
                        af[mi], bf[ni], acc[mi][ni], 0, 0, 0);
        }
    }

    #pragma unroll
    for (int mi = 0; mi < 4; ++mi) {
        #pragma unroll
        for (int r = 0; r < 4; ++r) {
            const int grow = row0 + wm + mi * 16 + quad * 4 + r;
            const int rt = tv[grow];
            const float* brow = bias + (size_t)rt * NDIM;
            float* orow = out + (size_t)grow * NDIM;
            #pragma unroll
            for (int ni = 0; ni < 4; ++ni) {
                const int gcol = col0 + wn + ni * 16 + l15;
                orow[gcol] = acc[mi][ni][r] + brow[gcol];
            }
        }
    }
}

extern "C" void kernel_launch(void* const* d_in, const int* in_sizes, int n_in,
                              void* d_out, int out_size, void* d_ws, size_t ws_size,
                              hipStream_t stream) {
    const float* x    = (const float*)d_in[0];
    const int*   tv   = (const int*)d_in[1];
    const float* w    = (const float*)d_in[2];
    const float* bias = (const float*)d_in[3];
    float* out = (float*)d_out;

    unsigned short* wtr = (unsigned short*)d_ws;                 // 4 MiB
    const size_t WTN  = (size_t)8 * 512 * 512;                   // wtr elems
    const size_t NEED = WTN * 2 + (size_t)NROWS * KDIM * 2;      // 132 MiB

    if (ws_size >= NEED) {
        unsigned short* xb = wtr + WTN;                          // 128 MiB
        prep_kernel<<<2560, 256, 0, stream>>>(w, wtr, x, xb);
        hetero_gemm_256<<<1024, 512, 0, stream>>>(xb, tv, wtr, bias, out);
    } else {
        // fallback: transform W only, then round-0 proven GEMM
        prep_kernel<<<512, 256, 0, stream>>>(w, wtr, x, nullptr);
        hetero_gemm_fallback<<<4096, 256, 0, stream>>>(x, tv, wtr, bias, out);
    }
}